// Round 2
// baseline (207.203 us; speedup 1.0000x reference)
//
#include <hip/hip_runtime.h>

// MultiScaleSampler: per-point 5->32->32->32->3 MLP + softmax(3), scattered to
// zeroed (H*W,3) fp32 output at unique indices yi.
// R2 strategy: 2 points/thread (each wave-uniform s_loaded weight feeds 2 FMA
// chains), __launch_bounds__(256,3) to stop the VGPR=36 spill pathology seen
// in R1, own float4 fill kernel instead of hipMemsetAsync.

#define W_IMG 2048
#define NFEAT 32
#define NPROB 3

__global__ __launch_bounds__(256) void fill_zero(float* __restrict__ out, int n) {
    int n4 = n >> 2;
    float4* o4 = (float4*)out;
    int stride = gridDim.x * blockDim.x;
    for (int i = blockIdx.x * blockDim.x + threadIdx.x; i < n4; i += stride)
        o4[i] = make_float4(0.f, 0.f, 0.f, 0.f);
    // tail (n not multiple of 4)
    int t = (n4 << 2) + (blockIdx.x * blockDim.x + threadIdx.x);
    if (t < n) out[t] = 0.f;
}

__global__ __launch_bounds__(256, 3) void msampler_mlp(
    const float* __restrict__ grid,   // (2, N): x row then y row
    const int*   __restrict__ yi,     // (N,)
    const float* __restrict__ m,      // (3,3)
    const float* __restrict__ W1, const float* __restrict__ b1,   // (5,32),(32)
    const float* __restrict__ W2, const float* __restrict__ b2,   // (32,32),(32)
    const float* __restrict__ W3, const float* __restrict__ b3,   // (32,32),(32)
    const float* __restrict__ W4, const float* __restrict__ b4,   // (32,3),(3)
    float* __restrict__ out, int N)
{
    int t = blockIdx.x * blockDim.x + threadIdx.x;
    int i = t * 2;
    if (i >= N) return;

    // vectorized point loads (i even, N even -> 8B aligned)
    float2 gx = *(const float2*)(grid + i);
    float2 gy = *(const float2*)(grid + N + i);
    int2   y2 = *(const int2*)(yi + i);

    // uniform homography math (scalarizes to SGPRs)
    float m00=m[0], m01=m[1], m02=m[2];
    float m10=m[3], m11=m[4], m12=m[5];
    float m20=m[6], m21=m[7], m22=m[8];
    float det = m00*(m11*m22 - m12*m21)
              - m01*(m10*m22 - m12*m20)
              + m02*(m10*m21 - m11*m20);
    float adet = fabsf(det);

    // per-point features [fx, fy, 1-fx, 1-fy, dsda]
    float x0[2], x1[2], x2[2], x3[2], x4[2];
#pragma unroll
    for (int p = 0; p < 2; ++p) {
        float gxv = p ? gx.y : gx.x;
        float gyv = p ? gy.y : gy.x;
        int   y   = p ? y2.y : y2.x;
        int   py  = y >> 11;           // / 2048
        int   px  = y & (W_IMG - 1);   // % 2048
        float denom = m20*(float)px + m21*(float)py + m22;
        float ad = fabsf(denom);
        float fx = gxv - floorf(gxv);
        float fy = gyv - floorf(gyv);
        x0[p] = fx; x1[p] = fy; x2[p] = 1.f - fx; x3[p] = 1.f - fy;
        x4[p] = adet / (ad*ad*ad);
    }

    float ha[2][NFEAT], hb[2][NFEAT];

    // layer 1: (5 -> 32) + relu
#pragma unroll
    for (int j = 0; j < NFEAT; ++j) {
        float w0 = W1[0*NFEAT + j], w1 = W1[1*NFEAT + j], w2 = W1[2*NFEAT + j];
        float w3 = W1[3*NFEAT + j], w4 = W1[4*NFEAT + j], bb = b1[j];
#pragma unroll
        for (int p = 0; p < 2; ++p) {
            float a = bb;
            a = fmaf(x0[p], w0, a);
            a = fmaf(x1[p], w1, a);
            a = fmaf(x2[p], w2, a);
            a = fmaf(x3[p], w3, a);
            a = fmaf(x4[p], w4, a);
            ha[p][j] = fmaxf(a, 0.f);
        }
    }
    // layer 2: (32 -> 32) + relu
#pragma unroll
    for (int j = 0; j < NFEAT; ++j) {
        float a0 = b2[j], a1 = a0;
#pragma unroll
        for (int k = 0; k < NFEAT; ++k) {
            float w = W2[k*NFEAT + j];
            a0 = fmaf(ha[0][k], w, a0);
            a1 = fmaf(ha[1][k], w, a1);
        }
        hb[0][j] = fmaxf(a0, 0.f);
        hb[1][j] = fmaxf(a1, 0.f);
    }
    // layer 3: (32 -> 32) + relu (reuse ha)
#pragma unroll
    for (int j = 0; j < NFEAT; ++j) {
        float a0 = b3[j], a1 = a0;
#pragma unroll
        for (int k = 0; k < NFEAT; ++k) {
            float w = W3[k*NFEAT + j];
            a0 = fmaf(hb[0][k], w, a0);
            a1 = fmaf(hb[1][k], w, a1);
        }
        ha[0][j] = fmaxf(a0, 0.f);
        ha[1][j] = fmaxf(a1, 0.f);
    }
    // layer 4: (32 -> 3) + softmax + scatter
#pragma unroll
    for (int p = 0; p < 2; ++p) {
        float l0 = b4[0], l1 = b4[1], l2 = b4[2];
#pragma unroll
        for (int k = 0; k < NFEAT; ++k) {
            float h = ha[p][k];
            l0 = fmaf(h, W4[k*NPROB + 0], l0);
            l1 = fmaf(h, W4[k*NPROB + 1], l1);
            l2 = fmaf(h, W4[k*NPROB + 2], l2);
        }
        float mx = fmaxf(l0, fmaxf(l1, l2));
        float e0 = __expf(l0 - mx), e1 = __expf(l1 - mx), e2 = __expf(l2 - mx);
        float inv = 1.f / (e0 + e1 + e2);
        int y = p ? y2.y : y2.x;
        int o = y * 3;
        out[o + 0] = e0 * inv;
        out[o + 1] = e1 * inv;
        out[o + 2] = e2 * inv;
    }
}

extern "C" void kernel_launch(void* const* d_in, const int* in_sizes, int n_in,
                              void* d_out, int out_size, void* d_ws, size_t ws_size,
                              hipStream_t stream) {
    const float* grid = (const float*)d_in[0];
    const int*   yi   = (const int*)  d_in[1];
    const float* m    = (const float*)d_in[2];
    const float* W1   = (const float*)d_in[3];
    const float* b1   = (const float*)d_in[4];
    const float* W2   = (const float*)d_in[5];
    const float* b2   = (const float*)d_in[6];
    const float* W3   = (const float*)d_in[7];
    const float* b3   = (const float*)d_in[8];
    const float* W4   = (const float*)d_in[9];
    const float* b4   = (const float*)d_in[10];
    float* out = (float*)d_out;

    int N = in_sizes[1];  // yi element count

    // zero the spatial output with our own vectorized fill (probe the memset gap)
    fill_zero<<<1024, 256, 0, stream>>>(out, out_size);

    int npts_per_thread = 2;
    int threads = (N + npts_per_thread - 1) / npts_per_thread;
    int block = 256;
    int grid_sz = (threads + block - 1) / block;
    msampler_mlp<<<grid_sz, block, 0, stream>>>(
        grid, yi, m, W1, b1, W2, b2, W3, b3, W4, b4, out, N);
}